// Round 9
// baseline (312.381 us; speedup 1.0000x reference)
//
#include <hip/hip_runtime.h>
#include <math.h>

#define HDIM  1024
#define MDIM  2048
#define RSQRT_D 0.08838834764831844f   // 1/sqrt(128)

// ---- workspace layout (float offsets) ----
// memsetAsync zeroes [0, OFF_Z) = barriers + w + beta (81952 B).
// Everything else is full-write before read.
#define OFF_BAR   0        // 5 barriers x 17 ctrs x 32 uints = 2720 (128B-padded)
#define OFF_W     4096     // w[8][2048]        (P_w atomics; zeroed by memset)
#define OFF_BETA  20480    // beta[8]           (P_q atomics; zeroed by memset)
#define OFF_Z     20488    // Z[8]              (P_y block 0)
#define OFF_Q     20496    // q[1024]           (P_q)
#define OFF_FEAT  21520    // feat[1024]        (P_f)
#define OFF_Y     22544    // y[8][2048]        (P_y)
#define OFF_ZP    38928    // zpart[256][8]     (P_ab)
#define OFF_YBUF  41984    // ybuf[512][8][2048] (33.6 MB) -> end ~33.9 MB

__device__ __forceinline__ float dot4(float4 a, float4 b) {
  return a.x * b.x + a.y * b.y + a.z * b.z + a.w * b.w;
}
__device__ __forceinline__ void fma4(float4& acc, float s, float4 v) {
  acc.x = fmaf(s, v.x, acc.x); acc.y = fmaf(s, v.y, acc.y);
  acc.z = fmaf(s, v.z, acc.z); acc.w = fmaf(s, v.w, acc.w);
}
__device__ __forceinline__ void add4(float4& a, float4 v) {
  a.x += v.x; a.y += v.y; a.z += v.z; a.w += v.w;
}

// ---- tree grid barrier: 16 groups x 16 blocks, 128B-padded counters (R8-proven).
// Hang-proof: grid 256 = 1 block/CU resident; increment-before-spin.
__device__ __forceinline__ void gbar(unsigned* bar, int k, int bid, int tid) {
  __syncthreads();                      // drain this block's stores
  if (tid == 0) {
    unsigned* grp  = bar + (size_t)k * 17 * 32;   // 16 group ctrs, 128B apart
    unsigned* root = grp + 16 * 32;
    unsigned r = __hip_atomic_fetch_add(&grp[(bid & 15) * 32], 1u,
                                        __ATOMIC_ACQ_REL, __HIP_MEMORY_SCOPE_AGENT);
    if (r == 15u)                       // last of this 16-block group
      __hip_atomic_fetch_add(root, 1u, __ATOMIC_ACQ_REL, __HIP_MEMORY_SCOPE_AGENT);
    while (__hip_atomic_load(root, __ATOMIC_RELAXED, __HIP_MEMORY_SCOPE_AGENT) < 16u)
      __builtin_amdgcn_s_sleep(1);
    (void)__hip_atomic_load(root, __ATOMIC_ACQUIRE, __HIP_MEMORY_SCOPE_AGENT);
  }
  __syncthreads();
}

// ---- fused: all phases, 256 blocks x 1024 threads (1 block/CU, 16 waves/CU) ----
// LDS deliberately padded to 82 KB: 2 blocks/CU becomes LDS-infeasible (164>160),
// so the compiler has no occupancy incentive to squeeze VGPRs to 64 (R8's bug) and
// can use the full LB(1024,4) budget of 128 for P_ab's in-flight load pipeline.
__global__ __launch_bounds__(1024, 4) void fused(const float* __restrict__ x,
                                                 const float* __restrict__ mem,
                                                 const float* __restrict__ Wq,
                                                 const float* __restrict__ bq,
                                                 const float* __restrict__ Wk,
                                                 const float* __restrict__ bk,
                                                 const float* __restrict__ Wv,
                                                 const float* __restrict__ bv,
                                                 const float* __restrict__ Wo,
                                                 const float* __restrict__ bo,
                                                 float* __restrict__ ws,
                                                 float* __restrict__ out) {
  __shared__ __align__(16) float4 lbuf[5248];   // 82 KB (union of all phases + pad)
  unsigned* bar = (unsigned*)ws;                // OFF_BAR == 0
  int tid = threadIdx.x, lane = tid & 63, wv = tid >> 6;
  int bid = blockIdx.x;

  // ========= P_q: q[j] = x.Wq[j,:]+bq[j] (waves 0-3); beta via 8 atomics =========
  if (wv < 4) {
    int j = bid * 4 + wv;
    const float4* xr = (const float4*)x;
    const float4* wr = (const float4*)(Wq + (size_t)j * HDIM);
    float a = 0.f;
#pragma unroll
    for (int i = 0; i < 4; ++i) {
      int idx = i * 64 + lane;
      a += dot4(xr[idx], wr[idx]);
    }
#pragma unroll
    for (int off = 32; off; off >>= 1) a += __shfl_xor(a, off);
    if (lane == 0) {
      float qj = a + bq[j];
      ws[OFF_Q + j] = qj;
      atomicAdd(&ws[OFF_BETA + (j & 7)], qj * bk[j]);   // beta zeroed by memset
    }
  }
  gbar(bar, 0, bid, tid);

  // ========= P_w: w[n][m] += q[c]*Wk[c][m]  (all 256 blocks; 32 atomics/cell) =====
  {
    int mc = bid & 7, cc = bid >> 3;            // 8 m-chunks x 32 c-chunks
    int m = mc * 256 + (tid & 255);
    int g = tid >> 8;                            // 0..3: n in {g, g+4}
    int cb = cc * 32 + g;
    const float* q = ws + OFF_Q;
    float a0 = 0.f, a1 = 0.f;
#pragma unroll
    for (int k = 0; k < 4; ++k) {
      int c0 = cb + 8 * k;                       // n = g
      int c1 = cb + 4 + 8 * k;                   // n = g+4
      a0 = fmaf(q[c0], Wk[(size_t)c0 * MDIM + m], a0);
      a1 = fmaf(q[c1], Wk[(size_t)c1 * MDIM + m], a1);
    }
    atomicAdd(&ws[OFF_W + g * MDIM + m], a0);
    atomicAdd(&ws[OFF_W + (g + 4) * MDIM + m], a1);
  }
  gbar(bar, 1, bid, tid);

  // ========= P_ab: scores+softmax+weighted-sum (R6 kab body, 64 rows/block) =======
  {
    float4* wlds = lbuf;                  // w[8][2048], 64 KB
    float* pp = (float*)(lbuf + 4096);    // p[64][8]
    float* zz = pp + 512;                 // [16][8]
    float* bb = zz + 128;                 // beta[8]
    const float4* wsrc = (const float4*)(ws + OFF_W);
#pragma unroll
    for (int k = 0; k < 4; ++k)
      wlds[k * 1024 + tid] = wsrc[k * 1024 + tid];
    if (tid < 8) bb[tid] = ws[OFF_BETA + tid];

    int r0b = bid * 64;
    const float* rowp = mem + (size_t)(r0b + wv * 4) * MDIM;
    float4 mva[4], mvan[4], mvb[4];
#pragma unroll
    for (int i = 0; i < 4; ++i)
      mva[i] = *(const float4*)(rowp + (i * 64 + lane) * 4);
    __syncthreads();

    float zacc[8];
#pragma unroll
    for (int n = 0; n < 8; ++n) zacc[n] = 0.f;

#pragma unroll
    for (int rl = 0; rl < 4; ++rl) {
#pragma unroll
      for (int i = 0; i < 4; ++i)       // chunk1 of current row: issue early
        mvb[i] = *(const float4*)(rowp + 1024 + (i * 64 + lane) * 4);
      float acc[8];
#pragma unroll
      for (int n = 0; n < 8; ++n) acc[n] = 0.f;
#pragma unroll
      for (int pass = 0; pass < 4; ++pass) {
        int cq = pass * 64 + lane;
#pragma unroll
        for (int n = 0; n < 8; ++n) {
          float4 w4 = wlds[n * 512 + cq];
          acc[n] = fmaf(mva[pass].x, w4.x, acc[n]);
          acc[n] = fmaf(mva[pass].y, w4.y, acc[n]);
          acc[n] = fmaf(mva[pass].z, w4.z, acc[n]);
          acc[n] = fmaf(mva[pass].w, w4.w, acc[n]);
        }
      }
      if (rl < 3) {                     // prefetch next row's chunk0
#pragma unroll
        for (int i = 0; i < 4; ++i)
          mvan[i] = *(const float4*)(rowp + MDIM + (i * 64 + lane) * 4);
      }
#pragma unroll
      for (int pass = 0; pass < 4; ++pass) {
        int cq = 256 + pass * 64 + lane;
#pragma unroll
        for (int n = 0; n < 8; ++n) {
          float4 w4 = wlds[n * 512 + cq];
          acc[n] = fmaf(mvb[pass].x, w4.x, acc[n]);
          acc[n] = fmaf(mvb[pass].y, w4.y, acc[n]);
          acc[n] = fmaf(mvb[pass].z, w4.z, acc[n]);
          acc[n] = fmaf(mvb[pass].w, w4.w, acc[n]);
        }
      }
#pragma unroll
      for (int off = 1; off < 64; off <<= 1)
#pragma unroll
        for (int n = 0; n < 8; ++n)
          acc[n] += __shfl_xor(acc[n], off);
#pragma unroll
      for (int n = 0; n < 8; ++n) {
        float p = __expf((acc[n] + bb[n]) * RSQRT_D);
        zacc[n] += p;
        if (lane == 0) pp[(wv * 4 + rl) * 8 + n] = p;
      }
#pragma unroll
      for (int i = 0; i < 4; ++i) mva[i] = mvan[i];
      rowp += MDIM;
    }
    if (lane == 0) {
#pragma unroll
      for (int n = 0; n < 8; ++n) zz[wv * 8 + n] = zacc[n];
    }
    __syncthreads();
    if (tid < 8) {
      float z = 0.f;
#pragma unroll
      for (int w = 0; w < 16; ++w) z += zz[w * 8 + tid];
      ws[OFF_ZP + bid * 8 + tid] = z;
    }
    // phase B: y += p*mem for the block's 64 rows (L2/L3-hot), rows split by half
    int h = tid >> 9, t5 = tid & 511;
    float4 acc4[8];
#pragma unroll
    for (int n = 0; n < 8; ++n) acc4[n] = make_float4(0.f, 0.f, 0.f, 0.f);
    const float* base = mem + (size_t)(r0b + h * 32) * MDIM + t5 * 4;
    const float4* pp4 = (const float4*)pp + h * 64;   // (h*32+r)*2
#pragma unroll 4
    for (int r = 0; r < 32; ++r) {
      float4 mv = *(const float4*)(base + (size_t)r * MDIM);
      float4 pA = pp4[r * 2], pB = pp4[r * 2 + 1];    // broadcast
      fma4(acc4[0], pA.x, mv); fma4(acc4[1], pA.y, mv);
      fma4(acc4[2], pA.z, mv); fma4(acc4[3], pA.w, mv);
      fma4(acc4[4], pB.x, mv); fma4(acc4[5], pB.y, mv);
      fma4(acc4[6], pB.z, mv); fma4(acc4[7], pB.w, mv);
    }
    float* yb = ws + OFF_YBUF + (size_t)(bid * 2 + h) * 16384 + t5 * 4;
#pragma unroll
    for (int n = 0; n < 8; ++n)
      *(float4*)(yb + n * MDIM) = acc4[n];
  }
  gbar(bar, 2, bid, tid);

  // ========= P_y: y[quad] = sum_{512 slots} ybuf; block 0: Z ======================
  {
    float4* sA = lbuf;                  // [16 quads][stride 65] (bank-conflict pad)
    int ql = tid & 15, h64 = tid >> 4;  // 64 threads per quad
    int quad = bid * 16 + ql;
    const float4* src = (const float4*)(ws + OFF_YBUF);
    float4 a = make_float4(0.f, 0.f, 0.f, 0.f);
#pragma unroll
    for (int i = 0; i < 8; ++i)
      add4(a, src[(size_t)(h64 + 64 * i) * 4096 + quad]);
    sA[ql * 65 + h64] = a;
    __syncthreads();
    float4 v = sA[wv * 65 + lane];      // wave wv reduces quad wv (stride-1 read)
#pragma unroll
    for (int off = 1; off < 64; off <<= 1) {
      v.x += __shfl_xor(v.x, off);
      v.y += __shfl_xor(v.y, off);
      v.z += __shfl_xor(v.z, off);
      v.w += __shfl_xor(v.w, off);
    }
    if (lane == 0) ((float4*)(ws + OFF_Y))[bid * 16 + wv] = v;
    if (bid == 0) {                     // Z[n] = sum_{256 blocks} zpart[b][n]
      float* zzz = (float*)(lbuf + 2048);
      if (tid < 256) {
        int n = tid & 7;
        float z = 0.f;
#pragma unroll
        for (int i = 0; i < 8; ++i)
          z += ws[OFF_ZP + ((tid >> 3) + 32 * i) * 8 + n];
        z += __shfl_xor(z, 8); z += __shfl_xor(z, 16); z += __shfl_xor(z, 32);
        if (lane < 8) zzz[wv * 8 + lane] = z;
      }
      __syncthreads();
      if (tid < 8)
        ws[OFF_Z + tid] = zzz[tid] + zzz[8 + tid] + zzz[16 + tid] + zzz[24 + tid];
    }
  }
  gbar(bar, 3, bid, tid);

  // ========= P_f: feat[c] = (y[c&7].Wv[c,:])/Z + bv (waves 0-3) ===================
  if (wv < 4) {
    int c = bid * 4 + wv, n = c & 7;
    const float4* yb4 = (const float4*)(ws + OFF_Y + n * MDIM);
    const float4* wb4 = (const float4*)(Wv + (size_t)c * MDIM);
    float a = 0.f;
#pragma unroll
    for (int s = 0; s < 8; ++s) {
      int idx = s * 64 + lane;
      a += dot4(yb4[idx], wb4[idx]);
    }
#pragma unroll
    for (int off = 32; off; off >>= 1) a += __shfl_xor(a, off);
    if (lane == 0) ws[OFF_FEAT + c] = a / ws[OFF_Z + n] + bv[c];
  }
  gbar(bar, 4, bid, tid);

  // ========= P_o: out[j] = relu(x.Wo + feat.Wo + bo) (waves 0-3) ==================
  if (wv < 4) {
    int j = bid * 4 + wv;
    const float4* wb = (const float4*)(Wo + (size_t)j * 2048);
    const float4* xr = (const float4*)x;
    const float4* fr = (const float4*)(ws + OFF_FEAT);
    float a = 0.f;
#pragma unroll
    for (int s = 0; s < 4; ++s) {
      int idx = s * 64 + lane;
      a += dot4(xr[idx], wb[idx]);
      a += dot4(fr[idx], wb[256 + idx]);
    }
#pragma unroll
    for (int off = 32; off; off >>= 1) a += __shfl_xor(a, off);
    if (lane == 0) out[j] = fmaxf(a + bo[j], 0.f);
  }
}

extern "C" void kernel_launch(void* const* d_in, const int* in_sizes, int n_in,
                              void* d_out, int out_size, void* d_ws, size_t ws_size,
                              hipStream_t stream) {
  const float* x   = (const float*)d_in[0];
  const float* mem = (const float*)d_in[1];
  const float* Wq  = (const float*)d_in[2];
  const float* bq  = (const float*)d_in[3];
  const float* Wk  = (const float*)d_in[4];
  const float* bk  = (const float*)d_in[5];
  const float* Wv  = (const float*)d_in[6];
  const float* bv  = (const float*)d_in[7];
  const float* Wo  = (const float*)d_in[8];
  const float* bo  = (const float*)d_in[9];
  float* ws  = (float*)d_ws;
  float* out = (float*)d_out;

  // zero barriers + w + beta (81952 B)
  hipMemsetAsync(ws, 0, (OFF_Z) * sizeof(float), stream);

  fused<<<256, 1024, 0, stream>>>(x, mem, Wq, bq, Wk, bk, Wv, bv, Wo, bo, ws, out);
}

// Round 10
// 273.250 us; speedup vs baseline: 1.1432x; 1.1432x over previous
//
#include <hip/hip_runtime.h>
#include <math.h>

#define HDIM  1024
#define MDIM  2048
#define RSQRT_D 0.08838834764831844f   // 1/sqrt(128)

// ---- workspace layout (float offsets) ----
// w zeroed by kq (kw atomics). Barrier counters zeroed by kq (kyfo2 spins).
// Everything else full-write before read.
#define OFF_W     0          // w[8][2048]      (kw, atomic accum; zeroed by kq)
#define OFF_BETA  16384      // beta[8]         (kw block 256, non-atomic)
#define OFF_Z     16392      // Z[8]            (kyfo2 block 0, non-atomic)
#define OFF_Q     16400      // q[1024]         (kq)
#define OFF_FEAT  17424      // feat[1024]      (kyfo2 P_f)
#define OFF_Y     18448      // y[8][2048]      (kyfo2 P_y)
#define OFF_ZP    34832      // zpart[512][8]   (kab)
#define OFF_BAR   38928      // 2 barriers x 17 ctrs x 32 uints = 1088 (zeroed by kq)
#define OFF_YBUF  41984      // ybuf[512][8][2048] (kab, 33.6 MB) -> end ~33.9 MB

__device__ __forceinline__ float dot4(float4 a, float4 b) {
  return a.x * b.x + a.y * b.y + a.z * b.z + a.w * b.w;
}
__device__ __forceinline__ void fma4(float4& acc, float s, float4 v) {
  acc.x = fmaf(s, v.x, acc.x); acc.y = fmaf(s, v.y, acc.y);
  acc.z = fmaf(s, v.z, acc.z); acc.w = fmaf(s, v.w, acc.w);
}
__device__ __forceinline__ void add4(float4& a, float4 v) {
  a.x += v.x; a.y += v.y; a.z += v.z; a.w += v.w;
}

// ---- tree grid barrier: 16 groups x 16 blocks, 128B-padded counters.
// Proven safe+cheap in R8/R9 (plain launch, 256 blocks <= 256 CUs resident,
// increment-before-spin). ~4-6 us per barrier vs ~20-25 for a flat counter (R7).
__device__ __forceinline__ void gbar(unsigned* bar, int k, int bid, int tid) {
  __syncthreads();                      // drain this block's stores
  if (tid == 0) {
    unsigned* grp  = bar + (size_t)k * 17 * 32;   // 16 group ctrs, 128B apart
    unsigned* root = grp + 16 * 32;
    unsigned r = __hip_atomic_fetch_add(&grp[(bid & 15) * 32], 1u,
                                        __ATOMIC_ACQ_REL, __HIP_MEMORY_SCOPE_AGENT);
    if (r == 15u)                       // last of this 16-block group
      __hip_atomic_fetch_add(root, 1u, __ATOMIC_ACQ_REL, __HIP_MEMORY_SCOPE_AGENT);
    while (__hip_atomic_load(root, __ATOMIC_RELAXED, __HIP_MEMORY_SCOPE_AGENT) < 16u)
      __builtin_amdgcn_s_sleep(1);
    (void)__hip_atomic_load(root, __ATOMIC_ACQUIRE, __HIP_MEMORY_SCOPE_AGENT);
  }
  __syncthreads();
}

// ---- kq: q[j] = x.Wq[j,:] + bq[j] (wave per j); zeroes w + barrier counters ----
__global__ __launch_bounds__(256) void kq(const float* __restrict__ x,
                                          const float* __restrict__ Wq,
                                          const float* __restrict__ bq,
                                          float* __restrict__ ws) {
  int tid = threadIdx.x, lane = tid & 63;
  int j = blockIdx.x * 4 + (tid >> 6);
  const float4* xr = (const float4*)x;
  const float4* wr = (const float4*)(Wq + (size_t)j * HDIM);
  float acc = 0.f;
#pragma unroll
  for (int i = 0; i < 4; ++i) {
    int idx = i * 64 + lane;
    acc += dot4(xr[idx], wr[idx]);
  }
#pragma unroll
  for (int off = 32; off; off >>= 1) acc += __shfl_xor(acc, off);
  if (lane == 0) ws[OFF_Q + j] = acc + bq[j];
  // zero w slice: 16384 floats / 256 blocks = 64 per block
  if (tid < 64) ws[OFF_W + blockIdx.x * 64 + tid] = 0.f;
  // zero kyfo2's barrier counters (1088 uints, blocks 0-4)
  int z = blockIdx.x * 256 + tid;
  if (z < 1088) ((unsigned*)(ws + OFF_BAR))[z] = 0u;
}

// ---- kw: w[n][m] += q[c]*Wk[c][m] (c-chunked atomics, grid 256);
//          block 256: beta[n] = sum_{c%8==n} q[c]*bk[c] (non-atomic) ----
__global__ __launch_bounds__(256) void kw(const float* __restrict__ Wk,
                                          const float* __restrict__ bk,
                                          float* __restrict__ ws) {
  __shared__ float lds[32];
  int tid = threadIdx.x;
  const float* q = ws + OFF_Q;
  if (blockIdx.x == 256) {   // beta block
    float b = 0.f;
#pragma unroll
    for (int i = 0; i < 4; ++i) {
      int c = tid + 256 * i;
      b = fmaf(q[c], bk[c], b);
    }
    b += __shfl_xor(b, 8); b += __shfl_xor(b, 16); b += __shfl_xor(b, 32);
    if ((tid & 63) < 8) lds[(tid >> 6) * 8 + (tid & 7)] = b;
    __syncthreads();
    if (tid < 8)
      ws[OFF_BETA + tid] = lds[tid] + lds[8 + tid] + lds[16 + tid] + lds[24 + tid];
    return;
  }
  int mc = blockIdx.x & 7, cc = blockIdx.x >> 3;   // 8 m-chunks x 32 c-chunks
  int m = mc * 256 + tid;
  float acc[8];
#pragma unroll
  for (int n = 0; n < 8; ++n) acc[n] = 0.f;
  int c0 = cc * 32;
#pragma unroll
  for (int cb = 0; cb < 32; cb += 8) {
#pragma unroll
    for (int u = 0; u < 8; ++u)
      acc[u] = fmaf(q[c0 + cb + u], Wk[(size_t)(c0 + cb + u) * MDIM + m], acc[u]);
  }
#pragma unroll
  for (int n = 0; n < 8; ++n) atomicAdd(&ws[OFF_W + n * MDIM + m], acc[n]);
}

// ---- kab: fused scores + softmax + weighted-sum (R6-proven, VERBATIM).
// Grid 512 x 512 threads, LB(512,4) -> 2 blocks/CU, compiler unconstrained. ----
__global__ __launch_bounds__(512, 4) void kab(const float* __restrict__ mem,
                                              float* __restrict__ ws) {
  __shared__ float4 wlds[4096];            // w[8][2048] staged, 64 KB
  __shared__ __align__(16) float pp[256];  // p[32 rows][8 heads]
  __shared__ float zz[64];
  __shared__ float bb[8];
  int tid = threadIdx.x, lane = tid & 63, wv = tid >> 6;
  int bid = blockIdx.x;
  int r0 = bid * 32;

  const float4* wsrc = (const float4*)(ws + OFF_W);
#pragma unroll
  for (int k = 0; k < 8; ++k)
    wlds[k * 512 + tid] = wsrc[k * 512 + tid];
  if (tid < 8) bb[tid] = ws[OFF_BETA + tid];

  const float* rowp = mem + (size_t)(r0 + wv * 4) * MDIM;
  float4 mva[4], mvan[4], mvb[4];
#pragma unroll
  for (int i = 0; i < 4; ++i)
    mva[i] = *(const float4*)(rowp + (i * 64 + lane) * 4);
  __syncthreads();

  float zacc[8];
#pragma unroll
  for (int n = 0; n < 8; ++n) zacc[n] = 0.f;

#pragma unroll
  for (int rl = 0; rl < 4; ++rl) {
    // chunk1 (cols 1024..2047) of current row: issue early
#pragma unroll
    for (int i = 0; i < 4; ++i)
      mvb[i] = *(const float4*)(rowp + 1024 + (i * 64 + lane) * 4);
    float acc[8];
#pragma unroll
    for (int n = 0; n < 8; ++n) acc[n] = 0.f;
#pragma unroll
    for (int pass = 0; pass < 4; ++pass) {
      int cq = pass * 64 + lane;
#pragma unroll
      for (int n = 0; n < 8; ++n) {
        float4 w4 = wlds[n * 512 + cq];
        acc[n] = fmaf(mva[pass].x, w4.x, acc[n]);
        acc[n] = fmaf(mva[pass].y, w4.y, acc[n]);
        acc[n] = fmaf(mva[pass].z, w4.z, acc[n]);
        acc[n] = fmaf(mva[pass].w, w4.w, acc[n]);
      }
    }
    if (rl < 3) {   // prefetch next row's chunk0 under chunk1 compute + butterfly
#pragma unroll
      for (int i = 0; i < 4; ++i)
        mvan[i] = *(const float4*)(rowp + MDIM + (i * 64 + lane) * 4);
    }
#pragma unroll
    for (int pass = 0; pass < 4; ++pass) {
      int cq = 256 + pass * 64 + lane;
#pragma unroll
      for (int n = 0; n < 8; ++n) {
        float4 w4 = wlds[n * 512 + cq];
        acc[n] = fmaf(mvb[pass].x, w4.x, acc[n]);
        acc[n] = fmaf(mvb[pass].y, w4.y, acc[n]);
        acc[n] = fmaf(mvb[pass].z, w4.z, acc[n]);
        acc[n] = fmaf(mvb[pass].w, w4.w, acc[n]);
      }
    }
#pragma unroll
    for (int off = 1; off < 64; off <<= 1)
#pragma unroll
      for (int n = 0; n < 8; ++n)
        acc[n] += __shfl_xor(acc[n], off);
#pragma unroll
    for (int n = 0; n < 8; ++n) {
      float p = __expf((acc[n] + bb[n]) * RSQRT_D);
      zacc[n] += p;
      if (lane == 0) pp[(wv * 4 + rl) * 8 + n] = p;
    }
#pragma unroll
    for (int i = 0; i < 4; ++i) mva[i] = mvan[i];
    rowp += MDIM;
  }
  if (lane == 0) {
#pragma unroll
    for (int n = 0; n < 8; ++n) zz[wv * 8 + n] = zacc[n];
  }
  __syncthreads();
  if (tid < 8) {
    float z = 0.f;
#pragma unroll
    for (int w = 0; w < 8; ++w) z += zz[w * 8 + tid];
    ws[OFF_ZP + bid * 8 + tid] = z;
  }

  // ---- phase B: y += p * mem for the same 32 rows (L2/L3-hot re-read) ----
  float4 acc4[8];
#pragma unroll
  for (int n = 0; n < 8; ++n) acc4[n] = make_float4(0.f, 0.f, 0.f, 0.f);
  const float* base = mem + (size_t)r0 * MDIM + tid * 4;
  const float4* pp4 = (const float4*)pp;
#pragma unroll 4
  for (int r = 0; r < 32; ++r) {
    float4 mv = *(const float4*)(base + (size_t)r * MDIM);
    float4 pA = pp4[r * 2], pB = pp4[r * 2 + 1];   // broadcast
    fma4(acc4[0], pA.x, mv); fma4(acc4[1], pA.y, mv);
    fma4(acc4[2], pA.z, mv); fma4(acc4[3], pA.w, mv);
    fma4(acc4[4], pB.x, mv); fma4(acc4[5], pB.y, mv);
    fma4(acc4[6], pB.z, mv); fma4(acc4[7], pB.w, mv);
  }
  float* yb = ws + OFF_YBUF + (size_t)bid * 16384 + tid * 4;
#pragma unroll
  for (int n = 0; n < 8; ++n)
    *(float4*)(yb + n * MDIM) = acc4[n];
}

// ---- kyfo2: fused tail, 256 blocks x 1024 threads (16 waves/CU), tree barriers.
// P_y (R9-proven 1024-thr body, stride-65 pad) -> bar -> P_f -> bar -> P_o. ----
__global__ __launch_bounds__(1024, 4) void kyfo2(const float* __restrict__ x,
                                                 const float* __restrict__ Wv,
                                                 const float* __restrict__ bv,
                                                 const float* __restrict__ Wo,
                                                 const float* __restrict__ bo,
                                                 float* __restrict__ ws,
                                                 float* __restrict__ out) {
  __shared__ __align__(16) float4 sA[1040];   // [16 quads][stride 65], 16.6 KB
  __shared__ float zzz[32];
  unsigned* bar = (unsigned*)(ws + OFF_BAR);
  int tid = threadIdx.x, lane = tid & 63, wv = tid >> 6;
  int bid = blockIdx.x;

  // ---- P_y: y[quad] = sum_{512 slots} ybuf[slot][quad] ----
  {
    int ql = tid & 15, h64 = tid >> 4;  // 64 threads per quad
    int quad = bid * 16 + ql;
    const float4* src = (const float4*)(ws + OFF_YBUF);
    float4 a = make_float4(0.f, 0.f, 0.f, 0.f);
#pragma unroll
    for (int i = 0; i < 8; ++i)
      add4(a, src[(size_t)(h64 + 64 * i) * 4096 + quad]);
    sA[ql * 65 + h64] = a;
    __syncthreads();
    float4 v = sA[wv * 65 + lane];      // wave wv reduces quad wv (stride-1 read)
#pragma unroll
    for (int off = 1; off < 64; off <<= 1) {
      v.x += __shfl_xor(v.x, off);
      v.y += __shfl_xor(v.y, off);
      v.z += __shfl_xor(v.z, off);
      v.w += __shfl_xor(v.w, off);
    }
    if (lane == 0) ((float4*)(ws + OFF_Y))[bid * 16 + wv] = v;
  }
  if (bid == 0) {   // Z[n] = sum_{512 slots} zpart[b][n]
    if (tid < 256) {
      int n = tid & 7;
      float z = 0.f;
#pragma unroll
      for (int i = 0; i < 16; ++i)
        z += ws[OFF_ZP + ((tid >> 3) + 32 * i) * 8 + n];
      z += __shfl_xor(z, 8); z += __shfl_xor(z, 16); z += __shfl_xor(z, 32);
      if (lane < 8) zzz[(tid >> 6) * 8 + lane] = z;
    }
    __syncthreads();
    if (tid < 8)
      ws[OFF_Z + tid] = zzz[tid] + zzz[8 + tid] + zzz[16 + tid] + zzz[24 + tid];
  }
  gbar(bar, 0, bid, tid);

  // ---- P_f: feat[c] = (y[c&7].Wv[c,:])/Z[c&7] + bv[c] (waves 0-3) ----
  if (wv < 4) {
    int c = bid * 4 + wv, n = c & 7;
    const float4* yb4 = (const float4*)(ws + OFF_Y + n * MDIM);
    const float4* wb4 = (const float4*)(Wv + (size_t)c * MDIM);
    float a = 0.f;
#pragma unroll
    for (int s = 0; s < 8; ++s) {
      int idx = s * 64 + lane;
      a += dot4(yb4[idx], wb4[idx]);
    }
#pragma unroll
    for (int off = 32; off; off >>= 1) a += __shfl_xor(a, off);
    if (lane == 0) ws[OFF_FEAT + c] = a / ws[OFF_Z + n] + bv[c];
  }
  gbar(bar, 1, bid, tid);

  // ---- P_o: out[j] = relu(x.Wo[j,:1024] + feat.Wo[j,1024:] + bo[j]) (waves 0-3) ----
  if (wv < 4) {
    int j = bid * 4 + wv;
    const float4* wb = (const float4*)(Wo + (size_t)j * 2048);
    const float4* xr = (const float4*)x;
    const float4* fr = (const float4*)(ws + OFF_FEAT);
    float a = 0.f;
#pragma unroll
    for (int s = 0; s < 4; ++s) {
      int idx = s * 64 + lane;
      a += dot4(xr[idx], wb[idx]);
      a += dot4(fr[idx], wb[256 + idx]);
    }
#pragma unroll
    for (int off = 32; off; off >>= 1) a += __shfl_xor(a, off);
    if (lane == 0) out[j] = fmaxf(a + bo[j], 0.f);
  }
}

extern "C" void kernel_launch(void* const* d_in, const int* in_sizes, int n_in,
                              void* d_out, int out_size, void* d_ws, size_t ws_size,
                              hipStream_t stream) {
  const float* x   = (const float*)d_in[0];
  const float* mem = (const float*)d_in[1];
  const float* Wq  = (const float*)d_in[2];
  const float* bq  = (const float*)d_in[3];
  const float* Wk  = (const float*)d_in[4];
  const float* bk  = (const float*)d_in[5];
  const float* Wv  = (const float*)d_in[6];
  const float* bv  = (const float*)d_in[7];
  const float* Wo  = (const float*)d_in[8];
  const float* bo  = (const float*)d_in[9];
  float* ws  = (float*)d_ws;
  float* out = (float*)d_out;

  kq   <<<256, 256,  0, stream>>>(x, Wq, bq, ws);
  kw   <<<257, 256,  0, stream>>>(Wk, bk, ws);
  kab  <<<512, 512,  0, stream>>>(mem, ws);
  kyfo2<<<256, 1024, 0, stream>>>(x, Wv, bv, Wo, bo, ws, out);
}